// Round 10
// baseline (866.986 us; speedup 1.0000x reference)
//
#include <hip/hip_runtime.h>
#include <cstdint>
#include <cstddef>

#define KNN 16
#define NPTS 256
#define NBATCH 128

static constexpr float BN_SCALE_F = 0.9999950000374997f; // 1/sqrt(1+1e-5)

__device__ inline unsigned int f32_ord(float f) {
    unsigned int u = __float_as_uint(f);
    return (u & 0x80000000u) ? ~u : (u | 0x80000000u);
}

// Ws column gap map: stride 160 (=0 mod 32); 16-blocks shifted by 4 banks.
__device__ __forceinline__ int wmap(int n) { return n + 4 * (n >> 4); }

// ---------------------------------------------------------------------------
// sq[t] = sum_d x[t][d]^2, sequential fmaf chain (matches reference assoc).
// ---------------------------------------------------------------------------
template<int D>
__global__ __launch_bounds__(256) void sq_kernel(const float* __restrict__ x,
                                                 float* __restrict__ sq) {
    const int t = blockIdx.x * 256 + threadIdx.x;
    const float* r = x + (size_t)t * D;
    float s = 0.f;
    #pragma unroll
    for (int d = 0; d < D; ++d) s = fmaf(r[d], r[d], s);
    sq[t] = s;
}

// ---------------------------------------------------------------------------
// FUSED kNN v3: 32 i-rows/block, 1024 blocks (r9 grid) + register-pressure fix
// (r9 failed at VGPR 176 / 7.8% occ from its 8-wide merge arrays):
//  - two-stage merge: 2-way (scalars only) then the r8-proven 4-way
//  - __launch_bounds__(256,4) pins <=128 VGPR (4 blocks/CU)
//  - one 38.4KB LDS union: tiles region reused by the ladder dump
// Distance tile 32x64, 2x4 acc/thread, ascending-d fmaf chain -> d2
// bit-identical to r1..r9. Selection: 8 channels/row x 8 cands/tile u32
// ladders (strict <, j ascending per thread); both merge stages use explicit
// (value,index) lexicographic tie-break -> exact lax.top_k semantics.
// ---------------------------------------------------------------------------
template<int D>
__global__ __launch_bounds__(256, 4) void knn_fused_kernel(
        const float* __restrict__ x, const float* __restrict__ sq,
        int* __restrict__ idx) {
    constexpr int KS = (D >= 16) ? 16 : D;
    const int t  = threadIdx.x;
    const int tx = t & 15, ty = t >> 4;      // gram: 16 j-grp x 16 i-grp
    const int sr = t >> 3, sc = t & 7;       // select: 32 rows x 8 channels
    const int b  = blockIdx.x >> 3;
    const int i0 = (blockIdx.x & 7) * 32;
    const int base = b * NPTS;

    // ---- LDS union (floats): phase A | phase B ----
    // A: As 16x36 [0,576) | Bs 16x68 [576,1664) | d2L 32x68 [1664,3840)
    // B: Kv 32x132 [0,4224) | Ki(u16) [4224,6336) | Mv 32x68 [6336,8512)
    //    | Mi(u16) [8512,9600)
    __shared__ float S[9600];
    float (*As)[36]  = (float (*)[36])(S);
    float (*Bs)[68]  = (float (*)[68])(S + 576);
    float (*d2L)[68] = (float (*)[68])(S + 1664);
    float (*Kv)[132] = (float (*)[132])(S);
    unsigned short (*Ki)[132] = (unsigned short (*)[132])(S + 4224);
    float (*Mv)[68]  = (float (*)[68])(S + 6336);
    unsigned short (*Mi)[68] = (unsigned short (*)[68])(S + 8512);

    unsigned int Lv[16], Li[16];
    #pragma unroll
    for (int q = 0; q < 16; ++q) { Lv[q] = 0xFFFFFFFFu; Li[q] = 0u; }

    for (int jt = 0; jt < 4; ++jt) {
        const int j0 = jt * 64;
        float acc[2][4] = {};
        for (int k0 = 0; k0 < D; k0 += KS) {
            if constexpr (D % 16 == 0) {
                const int r  = t >> 2;
                const int cq = (t & 3) * 4;
                if (t < 128) {               // A tile: 32 rows x 16 k
                    const float4 va = *(const float4*)(x + (size_t)(base + i0 + r) * D + k0 + cq);
                    As[cq + 0][r] = va.x; As[cq + 1][r] = va.y;
                    As[cq + 2][r] = va.z; As[cq + 3][r] = va.w;
                }
                {                            // B tile: 64 rows x 16 k
                    const float4 vb = *(const float4*)(x + (size_t)(base + j0 + r) * D + k0 + cq);
                    Bs[cq + 0][r] = vb.x; Bs[cq + 1][r] = vb.y;
                    Bs[cq + 2][r] = vb.z; Bs[cq + 3][r] = vb.w;
                }
            } else {
                for (int e = t; e < 32 * KS; e += 256) {
                    const int r = e / KS, c = e % KS;
                    As[c][r] = x[(size_t)(base + i0 + r) * D + k0 + c];
                }
                for (int e = t; e < 64 * KS; e += 256) {
                    const int r = e / KS, c = e % KS;
                    Bs[c][r] = x[(size_t)(base + j0 + r) * D + k0 + c];
                }
            }
            __syncthreads();
            #pragma unroll
            for (int kk = 0; kk < KS; ++kk) {
                const float2 av = *(const float2*)&As[kk][ty * 2];
                const float4 bv = *(const float4*)&Bs[kk][tx * 4];
                const float am[2] = {av.x, av.y};
                const float bm[4] = {bv.x, bv.y, bv.z, bv.w};
                #pragma unroll
                for (int m = 0; m < 2; ++m)
                    #pragma unroll
                    for (int n = 0; n < 4; ++n)
                        acc[m][n] = fmaf(am[m], bm[n], acc[m][n]);
            }
            __syncthreads();
        }

        // ---- epilogue: d2 tile into LDS (same arithmetic as r6..r9) ----
        float sqi[2], sqj[4];
        #pragma unroll
        for (int m = 0; m < 2; ++m) sqi[m] = sq[base + i0 + ty * 2 + m];
        #pragma unroll
        for (int n = 0; n < 4; ++n) sqj[n] = sq[base + j0 + tx * 4 + n];
        #pragma unroll
        for (int m = 0; m < 2; ++m) {
            const int gi = i0 + ty * 2 + m;
            #pragma unroll
            for (int n = 0; n < 4; ++n) {
                float v = (sqi[m] + sqj[n]) - 2.f * acc[m][n];
                if (gi == j0 + tx * 4 + n) v = INFINITY;
                d2L[ty * 2 + m][tx * 4 + n] = v;
            }
        }
        __syncthreads();

        // ---- insertion: thread (sr, sc) takes cands j = j0 + sc*8 + i ----
        float cand[8];
        *(float4*)&cand[0] = *(const float4*)&d2L[sr][sc * 8];
        *(float4*)&cand[4] = *(const float4*)&d2L[sr][sc * 8 + 4];
        #pragma unroll
        for (int i = 0; i < 8; ++i) {
            const unsigned int v = f32_ord(cand[i]);
            const unsigned int j = (unsigned int)(j0 + sc * 8 + i);
            #pragma unroll
            for (int q = 15; q >= 1; --q) {
                const bool a = v < Lv[q];
                const bool c = v < Lv[q - 1];
                Lv[q] = a ? (c ? Lv[q - 1] : v) : Lv[q];
                Li[q] = a ? (c ? Li[q - 1] : j) : Li[q];
            }
            const bool a0 = v < Lv[0];
            Lv[0] = a0 ? v : Lv[0];
            Li[0] = a0 ? j : Li[0];
        }
        __syncthreads();   // d2L reads done before next tile / phase B reuse
    }

    // ---- phase B: dump ladders (tiles region is dead now) ----
    #pragma unroll
    for (int q = 0; q < 16; ++q) {
        Kv[sr][sc * 16 + q] = __uint_as_float(Lv[q]);
        Ki[sr][sc * 16 + q] = (unsigned short)Li[q];
    }
    __syncthreads();

    // ---- stage 1: 2-way merge of adjacent channels (128 threads) ----
    if (t < 128) {
        const int row = t >> 2, p = t & 3;
        const int ca = p * 2, cb = p * 2 + 1;
        int ha = 0, hb = 0;
        unsigned int va = __float_as_uint(Kv[row][ca * 16]);
        unsigned int ia = Ki[row][ca * 16];
        unsigned int vb = __float_as_uint(Kv[row][cb * 16]);
        unsigned int ib = Ki[row][cb * 16];
        #pragma unroll
        for (int s = 0; s < 16; ++s) {
            const bool tb = (vb < va) | ((vb == va) & (ib < ia));
            Mv[row][p * 16 + s] = __uint_as_float(tb ? vb : va);
            Mi[row][p * 16 + s] = (unsigned short)(tb ? ib : ia);
            if (tb) {
                ++hb;
                vb = (hb < 16) ? __float_as_uint(Kv[row][cb * 16 + hb]) : 0xFFFFFFFFu;
                ib = (hb < 16) ? (unsigned int)Ki[row][cb * 16 + hb] : 0xFFFFu;
            } else {
                ++ha;
                va = (ha < 16) ? __float_as_uint(Kv[row][ca * 16 + ha]) : 0xFFFFFFFFu;
                ia = (ha < 16) ? (unsigned int)Ki[row][ca * 16 + ha] : 0xFFFFu;
            }
        }
    }
    __syncthreads();

    // ---- stage 2: 4-way tournament (32 threads, r8-proven) ----
    if (t < 32) {
        const int row = t;
        int h[4];
        unsigned int cv[4], ci[4];
        #pragma unroll
        for (int c = 0; c < 4; ++c) {
            h[c]  = 0;
            cv[c] = __float_as_uint(Mv[row][c * 16]);
            ci[c] = Mi[row][c * 16];
        }
        int outj[16];
        #pragma unroll
        for (int rd = 0; rd < 16; ++rd) {
            unsigned int bv = cv[0], bi = ci[0];
            int bc = 0;
            #pragma unroll
            for (int c = 1; c < 4; ++c) {
                const bool tk = (cv[c] < bv) | ((cv[c] == bv) & (ci[c] < bi));
                bv = tk ? cv[c] : bv;
                bi = tk ? ci[c] : bi;
                bc = tk ? c     : bc;
            }
            outj[rd] = (int)bi;
            #pragma unroll
            for (int c = 0; c < 4; ++c) {
                if (c == bc) {
                    const int hn = h[c] + 1;
                    h[c] = hn;
                    if (hn < 16) {
                        cv[c] = __float_as_uint(Mv[row][c * 16 + hn]);
                        ci[c] = Mi[row][c * 16 + hn];
                    } else {
                        cv[c] = 0xFFFFFFFFu;
                    }
                }
            }
        }
        int4* op = (int4*)(idx + (size_t)(base + i0 + row) * KNN);
        op[0] = make_int4(outj[0],  outj[1],  outj[2],  outj[3]);
        op[1] = make_int4(outj[4],  outj[5],  outj[6],  outj[7]);
        op[2] = make_int4(outj[8],  outj[9],  outj[10], outj[11]);
        op[3] = make_int4(outj[12], outj[13], outj[14], outj[15]);
    }
}

// ---------------------------------------------------------------------------
// Factorized edge-MLP GEMM (unchanged from r6/r7/r8).
// ---------------------------------------------------------------------------
template<int D, int C>
__global__ __launch_bounds__(256) void mlp_gemm_kernel(
        const float* __restrict__ x, const float* __restrict__ W,
        const float* __restrict__ bias, const float* __restrict__ g,
        const float* __restrict__ be,
        float* __restrict__ A, float* __restrict__ Bv) {
    constexpr int BM = 128;
    constexpr int KT = (D >= 16) ? 16 : D;
    const int t  = threadIdx.x;
    const int m0 = blockIdx.x * BM;
    const int n0 = blockIdx.y * 128;
    const int tx = t & 15;   // col group (8 cols)
    const int ty = t >> 4;   // row group (8 rows)

    __shared__ float Xs[KT][BM + 4];
    __shared__ float Ws[KT][160];      // gapped columns via wmap()

    float acc[8][8] = {};

    for (int k0 = 0; k0 < D; k0 += KT) {
        if constexpr (D % 16 == 0) {
            const int r  = t >> 1;          // 0..127
            const int cq = (t & 1) * 8;     // 0 or 8
            const float* src = x + (size_t)(m0 + r) * D + k0 + cq;
            const float4 v0 = *(const float4*)(src);
            const float4 v1 = *(const float4*)(src + 4);
            Xs[cq + 0][r] = v0.x; Xs[cq + 1][r] = v0.y;
            Xs[cq + 2][r] = v0.z; Xs[cq + 3][r] = v0.w;
            Xs[cq + 4][r] = v1.x; Xs[cq + 5][r] = v1.y;
            Xs[cq + 6][r] = v1.z; Xs[cq + 7][r] = v1.w;
        } else {
            for (int e = t; e < BM * KT; e += 256) {
                const int r = e / KT, c = e % KT;
                Xs[c][r] = x[(size_t)(m0 + r) * D + k0 + c];
            }
        }
        if constexpr (D % 16 == 0) {
            const int wk = t >> 4;           // 0..15 (k row)
            const int nq = (t & 15) * 8;     // col offset (8-block)
            const int mb = wmap(nq);         // mapped col base (contiguous 8)
            const int gn = n0 + nq;
            const int kr = k0 + wk;
            if (gn < C) {
                const float* pt = W + (size_t)kr * C + gn;
                const float* pb = W + (size_t)(D + kr) * C + gn;
                const float4 t0 = *(const float4*)(pt);
                const float4 t1 = *(const float4*)(pt + 4);
                const float4 b0 = *(const float4*)(pb);
                const float4 b1 = *(const float4*)(pb + 4);
                *(float4*)&Ws[wk][mb]     = make_float4(t0.x - b0.x, t0.y - b0.y,
                                                        t0.z - b0.z, t0.w - b0.w);
                *(float4*)&Ws[wk][mb + 4] = make_float4(t1.x - b1.x, t1.y - b1.y,
                                                        t1.z - b1.z, t1.w - b1.w);
            } else {
                const float* pb = W + (size_t)(D + kr) * C + (gn - C);
                *(float4*)&Ws[wk][mb]     = *(const float4*)(pb);
                *(float4*)&Ws[wk][mb + 4] = *(const float4*)(pb + 4);
            }
        } else {
            for (int e = t; e < KT * 128; e += 256) {
                const int k = e >> 7, n = e & 127;
                const int gn = n0 + n, kr = k0 + k;
                Ws[k][wmap(n)] = (gn < C)
                    ? W[(size_t)kr * C + gn] - W[(size_t)(D + kr) * C + gn]
                    : W[(size_t)(D + kr) * C + (gn - C)];
            }
        }
        __syncthreads();

        const int mc = wmap(tx * 8);
        #pragma unroll
        for (int kk = 0; kk < KT; ++kk) {
            float xm[8], wn[8];
            *(float4*)&xm[0] = *(const float4*)&Xs[kk][ty * 8];
            *(float4*)&xm[4] = *(const float4*)&Xs[kk][ty * 8 + 4];
            *(float4*)&wn[0] = *(const float4*)&Ws[kk][mc];
            *(float4*)&wn[4] = *(const float4*)&Ws[kk][mc + 4];
            #pragma unroll
            for (int m = 0; m < 8; ++m)
                #pragma unroll
                for (int n = 0; n < 8; ++n)
                    acc[m][n] = fmaf(xm[m], wn[n], acc[m][n]);
        }
        __syncthreads();
    }

    const int gn = n0 + tx * 8;
    if (gn < C) {
        float fac[8];
        #pragma unroll
        for (int e = 0; e < 8; ++e) fac[e] = g[gn + e] * BN_SCALE_F;
        #pragma unroll
        for (int m = 0; m < 8; ++m) {
            float o[8];
            #pragma unroll
            for (int e = 0; e < 8; ++e) o[e] = fac[e] * acc[m][e];
            float* dst = A + (size_t)(m0 + ty * 8 + m) * C + gn;
            *(float4*)(dst)     = make_float4(o[0], o[1], o[2], o[3]);
            *(float4*)(dst + 4) = make_float4(o[4], o[5], o[6], o[7]);
        }
    } else {
        const int cb = gn - C;
        float fac[8], bb[8], bee[8];
        #pragma unroll
        for (int e = 0; e < 8; ++e) {
            fac[e] = g[cb + e] * BN_SCALE_F;
            bb[e]  = bias[cb + e];
            bee[e] = be[cb + e];
        }
        #pragma unroll
        for (int m = 0; m < 8; ++m) {
            float o[8];
            #pragma unroll
            for (int e = 0; e < 8; ++e)
                o[e] = fmaf(fac[e], acc[m][e] + bb[e], bee[e]);
            float* dst = Bv + (size_t)(m0 + ty * 8 + m) * C + cb;
            *(float4*)(dst)     = make_float4(o[0], o[1], o[2], o[3]);
            *(float4*)(dst + 4) = make_float4(o[4], o[5], o[6], o[7]);
        }
    }
}

// ---------------------------------------------------------------------------
// Combine: out[i][c] = relu(A[i][c] + max_{j in knn(i)} Bv[j][c]). out aliases A.
// ---------------------------------------------------------------------------
template<int C>
__global__ __launch_bounds__(C) void combine_kernel(
        const float* A, const float* __restrict__ Bv,
        const int* __restrict__ idx, float* out) {
    const int bi = blockIdx.x;
    const int c  = threadIdx.x;
    __shared__ int nbr[KNN];
    if (c < KNN) nbr[c] = idx[(size_t)bi * KNN + c];
    __syncthreads();
    const int b0 = bi & ~255;
    float mx = -INFINITY;
    #pragma unroll
    for (int kk = 0; kk < KNN; ++kk)
        mx = fmaxf(mx, Bv[(size_t)(b0 + nbr[kk]) * C + c]);
    float a = A[(size_t)bi * C + c];
    out[(size_t)bi * C + c] = fmaxf(a + mx, 0.f);
}

// ---------------------------------------------------------------------------
// Head: global max-pool over N, then 2 tiny FCs. One block per batch.
// ---------------------------------------------------------------------------
__global__ __launch_bounds__(256) void head_kernel(
        const float* __restrict__ h3, const float* __restrict__ Wf1,
        const float* __restrict__ bf1, const float* __restrict__ gf,
        const float* __restrict__ bef, const float* __restrict__ Wf2,
        const float* __restrict__ bf2, float* __restrict__ out) {
    const int b   = blockIdx.x;
    const int tid = threadIdx.x;
    __shared__ float p[256];
    __shared__ float f[128];
    const float* hb = h3 + (size_t)b * NPTS * 256;
    float mx = -INFINITY;
    for (int n = 0; n < NPTS; ++n) mx = fmaxf(mx, hb[(size_t)n * 256 + tid]);
    p[tid] = mx;
    __syncthreads();
    if (tid < 128) {
        float acc = bf1[tid];
        for (int d = 0; d < 256; ++d)
            acc = fmaf(p[d], Wf1[(size_t)d * 128 + tid], acc);
        float v = gf[tid] * (acc * BN_SCALE_F) + bef[tid];
        f[tid] = fmaxf(v, 0.f);
    }
    __syncthreads();
    if (tid < 12) {
        float acc = bf2[tid];
        for (int d = 0; d < 128; ++d)
            acc = fmaf(f[d], Wf2[(size_t)d * 12 + tid], acc);
        out[(size_t)b * 12 + tid] = acc;
    }
}

extern "C" void kernel_launch(void* const* d_in, const int* in_sizes, int n_in,
                              void* d_out, int out_size, void* d_ws, size_t ws_size,
                              hipStream_t stream) {
    const float* x   = (const float*)d_in[0];
    const float* W1  = (const float*)d_in[1];
    const float* b1  = (const float*)d_in[2];
    const float* g1  = (const float*)d_in[3];
    const float* be1 = (const float*)d_in[4];
    const float* W2  = (const float*)d_in[5];
    const float* b2  = (const float*)d_in[6];
    const float* g2  = (const float*)d_in[7];
    const float* be2 = (const float*)d_in[8];
    const float* W3  = (const float*)d_in[9];
    const float* b3  = (const float*)d_in[10];
    const float* g3  = (const float*)d_in[11];
    const float* be3 = (const float*)d_in[12];
    const float* Wf1 = (const float*)d_in[13];
    const float* bf1 = (const float*)d_in[14];
    const float* gf  = (const float*)d_in[15];
    const float* bef = (const float*)d_in[16];
    const float* Wf2 = (const float*)d_in[17];
    const float* bf2 = (const float*)d_in[18];
    float* out = (float*)d_out;

    char* ws = (char*)d_ws;
    const size_t idx_bytes = (size_t)NBATCH * NPTS * KNN * sizeof(int);   // 2 MB
    const size_t reg_bytes = (size_t)NBATCH * NPTS * 256 * sizeof(float); // 32 MB
    int*   idx = (int*)ws;
    float* R1  = (float*)(ws + idx_bytes);
    float* R2  = (float*)(ws + idx_bytes + reg_bytes);
    float* R3  = (float*)(ws + idx_bytes + 2 * reg_bytes);
    float* sqb = (float*)(ws + idx_bytes + 3 * reg_bytes);                // 128 KB

    const int BN = NBATCH * NPTS;        // 32768 points
    const int KNN_GRID = NBATCH * 8;     // 1024 blocks (32 i-rows each)
    const int MB = BN / 128;             // 256 m-blocks for the MLP GEMM

    // ---- Layer 1: x (D=6) -> h1 (C=64) in R1 ----
    sq_kernel<6><<<BN / 256, 256, 0, stream>>>(x, sqb);
    knn_fused_kernel<6><<<KNN_GRID, 256, 0, stream>>>(x, sqb, idx);
    mlp_gemm_kernel<6, 64><<<dim3(MB, 1), 256, 0, stream>>>(
        x, W1, b1, g1, be1, R1, R2);
    combine_kernel<64><<<BN, 64, 0, stream>>>(R1, R2, idx, R1);   // h1 = R1

    // ---- Layer 2: h1 (D=64) -> h2 (C=128) in R2 ----
    sq_kernel<64><<<BN / 256, 256, 0, stream>>>(R1, sqb);
    knn_fused_kernel<64><<<KNN_GRID, 256, 0, stream>>>(R1, sqb, idx);
    mlp_gemm_kernel<64, 128><<<dim3(MB, 2), 256, 0, stream>>>(
        R1, W2, b2, g2, be2, R2, R3);
    combine_kernel<128><<<BN, 128, 0, stream>>>(R2, R3, idx, R2); // h2 = R2

    // ---- Layer 3: h2 (D=128) -> h3 (C=256) in R3 ----
    sq_kernel<128><<<BN / 256, 256, 0, stream>>>(R2, sqb);
    knn_fused_kernel<128><<<KNN_GRID, 256, 0, stream>>>(R2, sqb, idx);
    mlp_gemm_kernel<128, 256><<<dim3(MB, 4), 256, 0, stream>>>(
        R2, W3, b3, g3, be3, R3, R1);
    combine_kernel<256><<<BN, 256, 0, stream>>>(R3, R1, idx, R3); // h3 = R3

    // ---- Head ----
    head_kernel<<<NBATCH, 256, 0, stream>>>(R3, Wf1, bf1, gf, bef, Wf2, bf2, out);
}

// Round 11
// 539.626 us; speedup vs baseline: 1.6066x; 1.6066x over previous
//
#include <hip/hip_runtime.h>
#include <cstdint>
#include <cstddef>

#define KNN 16
#define NPTS 256
#define NBATCH 128

static constexpr float BN_SCALE_F = 0.9999950000374997f; // 1/sqrt(1+1e-5)

__device__ inline unsigned int f32_ord(float f) {
    unsigned int u = __float_as_uint(f);
    return (u & 0x80000000u) ? ~u : (u | 0x80000000u);
}

// Ws column gap map: stride 160 (=0 mod 32); 16-blocks shifted by 4 banks.
__device__ __forceinline__ int wmap(int n) { return n + 4 * (n >> 4); }

// ---------------------------------------------------------------------------
// sq[t] = sum_d x[t][d]^2, sequential fmaf chain (matches reference assoc).
// ---------------------------------------------------------------------------
template<int D>
__global__ __launch_bounds__(256) void sq_kernel(const float* __restrict__ x,
                                                 float* __restrict__ sq) {
    const int t = blockIdx.x * 256 + threadIdx.x;
    const float* r = x + (size_t)t * D;
    float s = 0.f;
    #pragma unroll
    for (int d = 0; d < D; ++d) s = fmaf(r[d], r[d], s);
    sq[t] = s;
}

// ---------------------------------------------------------------------------
// FUSED kNN v4 = r10 WITHOUT the waves/EU pin (r10's __launch_bounds__(256,4)
// forced VGPR 64 -> ladder state spilled to scratch -> 1.5 GB HBM traffic).
// Natural allocation keeps the 32-reg ladder in VGPRs.
// Structure: 32 i-rows/block, 1024 blocks; distance tile 32x64 (2x4
// acc/thread, ascending-d fmaf chain -> d2 bit-identical to r1..r10);
// selection: 8 channels/row x 8 cands/tile u32 insertion ladders, then
// two-stage merge (2-way scalar, then 4-way tournament), both with explicit
// (value,index) lexicographic tie-break -> exact lax.top_k semantics.
// ---------------------------------------------------------------------------
template<int D>
__global__ __launch_bounds__(256) void knn_fused_kernel(
        const float* __restrict__ x, const float* __restrict__ sq,
        int* __restrict__ idx) {
    constexpr int KS = (D >= 16) ? 16 : D;
    const int t  = threadIdx.x;
    const int tx = t & 15, ty = t >> 4;      // gram: 16 j-grp x 16 i-grp
    const int sr = t >> 3, sc = t & 7;       // select: 32 rows x 8 channels
    const int b  = blockIdx.x >> 3;
    const int i0 = (blockIdx.x & 7) * 32;
    const int base = b * NPTS;

    // ---- LDS union (floats): phase A | phase B ----
    // A: As 16x36 [0,576) | Bs 16x68 [576,1664) | d2L 32x68 [1664,3840)
    // B: Kv 32x132 [0,4224) | Ki(u16) [4224,6336) | Mv 32x68 [6336,8512)
    //    | Mi(u16) [8512,9600)
    __shared__ float S[9600];
    float (*As)[36]  = (float (*)[36])(S);
    float (*Bs)[68]  = (float (*)[68])(S + 576);
    float (*d2L)[68] = (float (*)[68])(S + 1664);
    float (*Kv)[132] = (float (*)[132])(S);
    unsigned short (*Ki)[132] = (unsigned short (*)[132])(S + 4224);
    float (*Mv)[68]  = (float (*)[68])(S + 6336);
    unsigned short (*Mi)[68] = (unsigned short (*)[68])(S + 8512);

    unsigned int Lv[16], Li[16];
    #pragma unroll
    for (int q = 0; q < 16; ++q) { Lv[q] = 0xFFFFFFFFu; Li[q] = 0u; }

    for (int jt = 0; jt < 4; ++jt) {
        const int j0 = jt * 64;
        float acc[2][4] = {};
        for (int k0 = 0; k0 < D; k0 += KS) {
            if constexpr (D % 16 == 0) {
                const int r  = t >> 2;
                const int cq = (t & 3) * 4;
                if (t < 128) {               // A tile: 32 rows x 16 k
                    const float4 va = *(const float4*)(x + (size_t)(base + i0 + r) * D + k0 + cq);
                    As[cq + 0][r] = va.x; As[cq + 1][r] = va.y;
                    As[cq + 2][r] = va.z; As[cq + 3][r] = va.w;
                }
                {                            // B tile: 64 rows x 16 k
                    const float4 vb = *(const float4*)(x + (size_t)(base + j0 + r) * D + k0 + cq);
                    Bs[cq + 0][r] = vb.x; Bs[cq + 1][r] = vb.y;
                    Bs[cq + 2][r] = vb.z; Bs[cq + 3][r] = vb.w;
                }
            } else {
                for (int e = t; e < 32 * KS; e += 256) {
                    const int r = e / KS, c = e % KS;
                    As[c][r] = x[(size_t)(base + i0 + r) * D + k0 + c];
                }
                for (int e = t; e < 64 * KS; e += 256) {
                    const int r = e / KS, c = e % KS;
                    Bs[c][r] = x[(size_t)(base + j0 + r) * D + k0 + c];
                }
            }
            __syncthreads();
            #pragma unroll
            for (int kk = 0; kk < KS; ++kk) {
                const float2 av = *(const float2*)&As[kk][ty * 2];
                const float4 bv = *(const float4*)&Bs[kk][tx * 4];
                const float am[2] = {av.x, av.y};
                const float bm[4] = {bv.x, bv.y, bv.z, bv.w};
                #pragma unroll
                for (int m = 0; m < 2; ++m)
                    #pragma unroll
                    for (int n = 0; n < 4; ++n)
                        acc[m][n] = fmaf(am[m], bm[n], acc[m][n]);
            }
            __syncthreads();
        }

        // ---- epilogue: d2 tile into LDS (same arithmetic as r6..r10) ----
        float sqi[2], sqj[4];
        #pragma unroll
        for (int m = 0; m < 2; ++m) sqi[m] = sq[base + i0 + ty * 2 + m];
        #pragma unroll
        for (int n = 0; n < 4; ++n) sqj[n] = sq[base + j0 + tx * 4 + n];
        #pragma unroll
        for (int m = 0; m < 2; ++m) {
            const int gi = i0 + ty * 2 + m;
            #pragma unroll
            for (int n = 0; n < 4; ++n) {
                float v = (sqi[m] + sqj[n]) - 2.f * acc[m][n];
                if (gi == j0 + tx * 4 + n) v = INFINITY;
                d2L[ty * 2 + m][tx * 4 + n] = v;
            }
        }
        __syncthreads();

        // ---- insertion: thread (sr, sc) takes cands j = j0 + sc*8 + i ----
        float cand[8];
        *(float4*)&cand[0] = *(const float4*)&d2L[sr][sc * 8];
        *(float4*)&cand[4] = *(const float4*)&d2L[sr][sc * 8 + 4];
        #pragma unroll
        for (int i = 0; i < 8; ++i) {
            const unsigned int v = f32_ord(cand[i]);
            const unsigned int j = (unsigned int)(j0 + sc * 8 + i);
            #pragma unroll
            for (int q = 15; q >= 1; --q) {
                const bool a = v < Lv[q];
                const bool c = v < Lv[q - 1];
                Lv[q] = a ? (c ? Lv[q - 1] : v) : Lv[q];
                Li[q] = a ? (c ? Li[q - 1] : j) : Li[q];
            }
            const bool a0 = v < Lv[0];
            Lv[0] = a0 ? v : Lv[0];
            Li[0] = a0 ? j : Li[0];
        }
        __syncthreads();   // d2L reads done before next tile / phase B reuse
    }

    // ---- phase B: dump ladders (tiles region is dead now) ----
    #pragma unroll
    for (int q = 0; q < 16; ++q) {
        Kv[sr][sc * 16 + q] = __uint_as_float(Lv[q]);
        Ki[sr][sc * 16 + q] = (unsigned short)Li[q];
    }
    __syncthreads();

    // ---- stage 1: 2-way merge of adjacent channels (128 threads) ----
    if (t < 128) {
        const int row = t >> 2, p = t & 3;
        const int ca = p * 2, cb = p * 2 + 1;
        int ha = 0, hb = 0;
        unsigned int va = __float_as_uint(Kv[row][ca * 16]);
        unsigned int ia = Ki[row][ca * 16];
        unsigned int vb = __float_as_uint(Kv[row][cb * 16]);
        unsigned int ib = Ki[row][cb * 16];
        #pragma unroll
        for (int s = 0; s < 16; ++s) {
            const bool tb = (vb < va) | ((vb == va) & (ib < ia));
            Mv[row][p * 16 + s] = __uint_as_float(tb ? vb : va);
            Mi[row][p * 16 + s] = (unsigned short)(tb ? ib : ia);
            if (tb) {
                ++hb;
                vb = (hb < 16) ? __float_as_uint(Kv[row][cb * 16 + hb]) : 0xFFFFFFFFu;
                ib = (hb < 16) ? (unsigned int)Ki[row][cb * 16 + hb] : 0xFFFFu;
            } else {
                ++ha;
                va = (ha < 16) ? __float_as_uint(Kv[row][ca * 16 + ha]) : 0xFFFFFFFFu;
                ia = (ha < 16) ? (unsigned int)Ki[row][ca * 16 + ha] : 0xFFFFu;
            }
        }
    }
    __syncthreads();

    // ---- stage 2: 4-way tournament (32 threads, r8-proven) ----
    if (t < 32) {
        const int row = t;
        int h[4];
        unsigned int cv[4], ci[4];
        #pragma unroll
        for (int c = 0; c < 4; ++c) {
            h[c]  = 0;
            cv[c] = __float_as_uint(Mv[row][c * 16]);
            ci[c] = Mi[row][c * 16];
        }
        int outj[16];
        #pragma unroll
        for (int rd = 0; rd < 16; ++rd) {
            unsigned int bv = cv[0], bi = ci[0];
            int bc = 0;
            #pragma unroll
            for (int c = 1; c < 4; ++c) {
                const bool tk = (cv[c] < bv) | ((cv[c] == bv) & (ci[c] < bi));
                bv = tk ? cv[c] : bv;
                bi = tk ? ci[c] : bi;
                bc = tk ? c     : bc;
            }
            outj[rd] = (int)bi;
            #pragma unroll
            for (int c = 0; c < 4; ++c) {
                if (c == bc) {
                    const int hn = h[c] + 1;
                    h[c] = hn;
                    if (hn < 16) {
                        cv[c] = __float_as_uint(Mv[row][c * 16 + hn]);
                        ci[c] = Mi[row][c * 16 + hn];
                    } else {
                        cv[c] = 0xFFFFFFFFu;
                    }
                }
            }
        }
        int4* op = (int4*)(idx + (size_t)(base + i0 + row) * KNN);
        op[0] = make_int4(outj[0],  outj[1],  outj[2],  outj[3]);
        op[1] = make_int4(outj[4],  outj[5],  outj[6],  outj[7]);
        op[2] = make_int4(outj[8],  outj[9],  outj[10], outj[11]);
        op[3] = make_int4(outj[12], outj[13], outj[14], outj[15]);
    }
}

// ---------------------------------------------------------------------------
// Factorized edge-MLP GEMM (unchanged from r6/r7/r8).
// ---------------------------------------------------------------------------
template<int D, int C>
__global__ __launch_bounds__(256) void mlp_gemm_kernel(
        const float* __restrict__ x, const float* __restrict__ W,
        const float* __restrict__ bias, const float* __restrict__ g,
        const float* __restrict__ be,
        float* __restrict__ A, float* __restrict__ Bv) {
    constexpr int BM = 128;
    constexpr int KT = (D >= 16) ? 16 : D;
    const int t  = threadIdx.x;
    const int m0 = blockIdx.x * BM;
    const int n0 = blockIdx.y * 128;
    const int tx = t & 15;   // col group (8 cols)
    const int ty = t >> 4;   // row group (8 rows)

    __shared__ float Xs[KT][BM + 4];
    __shared__ float Ws[KT][160];      // gapped columns via wmap()

    float acc[8][8] = {};

    for (int k0 = 0; k0 < D; k0 += KT) {
        if constexpr (D % 16 == 0) {
            const int r  = t >> 1;          // 0..127
            const int cq = (t & 1) * 8;     // 0 or 8
            const float* src = x + (size_t)(m0 + r) * D + k0 + cq;
            const float4 v0 = *(const float4*)(src);
            const float4 v1 = *(const float4*)(src + 4);
            Xs[cq + 0][r] = v0.x; Xs[cq + 1][r] = v0.y;
            Xs[cq + 2][r] = v0.z; Xs[cq + 3][r] = v0.w;
            Xs[cq + 4][r] = v1.x; Xs[cq + 5][r] = v1.y;
            Xs[cq + 6][r] = v1.z; Xs[cq + 7][r] = v1.w;
        } else {
            for (int e = t; e < BM * KT; e += 256) {
                const int r = e / KT, c = e % KT;
                Xs[c][r] = x[(size_t)(m0 + r) * D + k0 + c];
            }
        }
        if constexpr (D % 16 == 0) {
            const int wk = t >> 4;           // 0..15 (k row)
            const int nq = (t & 15) * 8;     // col offset (8-block)
            const int mb = wmap(nq);         // mapped col base (contiguous 8)
            const int gn = n0 + nq;
            const int kr = k0 + wk;
            if (gn < C) {
                const float* pt = W + (size_t)kr * C + gn;
                const float* pb = W + (size_t)(D + kr) * C + gn;
                const float4 t0 = *(const float4*)(pt);
                const float4 t1 = *(const float4*)(pt + 4);
                const float4 b0 = *(const float4*)(pb);
                const float4 b1 = *(const float4*)(pb + 4);
                *(float4*)&Ws[wk][mb]     = make_float4(t0.x - b0.x, t0.y - b0.y,
                                                        t0.z - b0.z, t0.w - b0.w);
                *(float4*)&Ws[wk][mb + 4] = make_float4(t1.x - b1.x, t1.y - b1.y,
                                                        t1.z - b1.z, t1.w - b1.w);
            } else {
                const float* pb = W + (size_t)(D + kr) * C + (gn - C);
                *(float4*)&Ws[wk][mb]     = *(const float4*)(pb);
                *(float4*)&Ws[wk][mb + 4] = *(const float4*)(pb + 4);
            }
        } else {
            for (int e = t; e < KT * 128; e += 256) {
                const int k = e >> 7, n = e & 127;
                const int gn = n0 + n, kr = k0 + k;
                Ws[k][wmap(n)] = (gn < C)
                    ? W[(size_t)kr * C + gn] - W[(size_t)(D + kr) * C + gn]
                    : W[(size_t)(D + kr) * C + (gn - C)];
            }
        }
        __syncthreads();

        const int mc = wmap(tx * 8);
        #pragma unroll
        for (int kk = 0; kk < KT; ++kk) {
            float xm[8], wn[8];
            *(float4*)&xm[0] = *(const float4*)&Xs[kk][ty * 8];
            *(float4*)&xm[4] = *(const float4*)&Xs[kk][ty * 8 + 4];
            *(float4*)&wn[0] = *(const float4*)&Ws[kk][mc];
            *(float4*)&wn[4] = *(const float4*)&Ws[kk][mc + 4];
            #pragma unroll
            for (int m = 0; m < 8; ++m)
                #pragma unroll
                for (int n = 0; n < 8; ++n)
                    acc[m][n] = fmaf(xm[m], wn[n], acc[m][n]);
        }
        __syncthreads();
    }

    const int gn = n0 + tx * 8;
    if (gn < C) {
        float fac[8];
        #pragma unroll
        for (int e = 0; e < 8; ++e) fac[e] = g[gn + e] * BN_SCALE_F;
        #pragma unroll
        for (int m = 0; m < 8; ++m) {
            float o[8];
            #pragma unroll
            for (int e = 0; e < 8; ++e) o[e] = fac[e] * acc[m][e];
            float* dst = A + (size_t)(m0 + ty * 8 + m) * C + gn;
            *(float4*)(dst)     = make_float4(o[0], o[1], o[2], o[3]);
            *(float4*)(dst + 4) = make_float4(o[4], o[5], o[6], o[7]);
        }
    } else {
        const int cb = gn - C;
        float fac[8], bb[8], bee[8];
        #pragma unroll
        for (int e = 0; e < 8; ++e) {
            fac[e] = g[cb + e] * BN_SCALE_F;
            bb[e]  = bias[cb + e];
            bee[e] = be[cb + e];
        }
        #pragma unroll
        for (int m = 0; m < 8; ++m) {
            float o[8];
            #pragma unroll
            for (int e = 0; e < 8; ++e)
                o[e] = fmaf(fac[e], acc[m][e] + bb[e], bee[e]);
            float* dst = Bv + (size_t)(m0 + ty * 8 + m) * C + cb;
            *(float4*)(dst)     = make_float4(o[0], o[1], o[2], o[3]);
            *(float4*)(dst + 4) = make_float4(o[4], o[5], o[6], o[7]);
        }
    }
}

// ---------------------------------------------------------------------------
// Combine: out[i][c] = relu(A[i][c] + max_{j in knn(i)} Bv[j][c]). out aliases A.
// ---------------------------------------------------------------------------
template<int C>
__global__ __launch_bounds__(C) void combine_kernel(
        const float* A, const float* __restrict__ Bv,
        const int* __restrict__ idx, float* out) {
    const int bi = blockIdx.x;
    const int c  = threadIdx.x;
    __shared__ int nbr[KNN];
    if (c < KNN) nbr[c] = idx[(size_t)bi * KNN + c];
    __syncthreads();
    const int b0 = bi & ~255;
    float mx = -INFINITY;
    #pragma unroll
    for (int kk = 0; kk < KNN; ++kk)
        mx = fmaxf(mx, Bv[(size_t)(b0 + nbr[kk]) * C + c]);
    float a = A[(size_t)bi * C + c];
    out[(size_t)bi * C + c] = fmaxf(a + mx, 0.f);
}

// ---------------------------------------------------------------------------
// Head: global max-pool over N, then 2 tiny FCs. One block per batch.
// ---------------------------------------------------------------------------
__global__ __launch_bounds__(256) void head_kernel(
        const float* __restrict__ h3, const float* __restrict__ Wf1,
        const float* __restrict__ bf1, const float* __restrict__ gf,
        const float* __restrict__ bef, const float* __restrict__ Wf2,
        const float* __restrict__ bf2, float* __restrict__ out) {
    const int b   = blockIdx.x;
    const int tid = threadIdx.x;
    __shared__ float p[256];
    __shared__ float f[128];
    const float* hb = h3 + (size_t)b * NPTS * 256;
    float mx = -INFINITY;
    for (int n = 0; n < NPTS; ++n) mx = fmaxf(mx, hb[(size_t)n * 256 + tid]);
    p[tid] = mx;
    __syncthreads();
    if (tid < 128) {
        float acc = bf1[tid];
        for (int d = 0; d < 256; ++d)
            acc = fmaf(p[d], Wf1[(size_t)d * 128 + tid], acc);
        float v = gf[tid] * (acc * BN_SCALE_F) + bef[tid];
        f[tid] = fmaxf(v, 0.f);
    }
    __syncthreads();
    if (tid < 12) {
        float acc = bf2[tid];
        for (int d = 0; d < 128; ++d)
            acc = fmaf(f[d], Wf2[(size_t)d * 12 + tid], acc);
        out[(size_t)b * 12 + tid] = acc;
    }
}

extern "C" void kernel_launch(void* const* d_in, const int* in_sizes, int n_in,
                              void* d_out, int out_size, void* d_ws, size_t ws_size,
                              hipStream_t stream) {
    const float* x   = (const float*)d_in[0];
    const float* W1  = (const float*)d_in[1];
    const float* b1  = (const float*)d_in[2];
    const float* g1  = (const float*)d_in[3];
    const float* be1 = (const float*)d_in[4];
    const float* W2  = (const float*)d_in[5];
    const float* b2  = (const float*)d_in[6];
    const float* g2  = (const float*)d_in[7];
    const float* be2 = (const float*)d_in[8];
    const float* W3  = (const float*)d_in[9];
    const float* b3  = (const float*)d_in[10];
    const float* g3  = (const float*)d_in[11];
    const float* be3 = (const float*)d_in[12];
    const float* Wf1 = (const float*)d_in[13];
    const float* bf1 = (const float*)d_in[14];
    const float* gf  = (const float*)d_in[15];
    const float* bef = (const float*)d_in[16];
    const float* Wf2 = (const float*)d_in[17];
    const float* bf2 = (const float*)d_in[18];
    float* out = (float*)d_out;

    char* ws = (char*)d_ws;
    const size_t idx_bytes = (size_t)NBATCH * NPTS * KNN * sizeof(int);   // 2 MB
    const size_t reg_bytes = (size_t)NBATCH * NPTS * 256 * sizeof(float); // 32 MB
    int*   idx = (int*)ws;
    float* R1  = (float*)(ws + idx_bytes);
    float* R2  = (float*)(ws + idx_bytes + reg_bytes);
    float* R3  = (float*)(ws + idx_bytes + 2 * reg_bytes);
    float* sqb = (float*)(ws + idx_bytes + 3 * reg_bytes);                // 128 KB

    const int BN = NBATCH * NPTS;        // 32768 points
    const int KNN_GRID = NBATCH * 8;     // 1024 blocks (32 i-rows each)
    const int MB = BN / 128;             // 256 m-blocks for the MLP GEMM

    // ---- Layer 1: x (D=6) -> h1 (C=64) in R1 ----
    sq_kernel<6><<<BN / 256, 256, 0, stream>>>(x, sqb);
    knn_fused_kernel<6><<<KNN_GRID, 256, 0, stream>>>(x, sqb, idx);
    mlp_gemm_kernel<6, 64><<<dim3(MB, 1), 256, 0, stream>>>(
        x, W1, b1, g1, be1, R1, R2);
    combine_kernel<64><<<BN, 64, 0, stream>>>(R1, R2, idx, R1);   // h1 = R1

    // ---- Layer 2: h1 (D=64) -> h2 (C=128) in R2 ----
    sq_kernel<64><<<BN / 256, 256, 0, stream>>>(R1, sqb);
    knn_fused_kernel<64><<<KNN_GRID, 256, 0, stream>>>(R1, sqb, idx);
    mlp_gemm_kernel<64, 128><<<dim3(MB, 2), 256, 0, stream>>>(
        R1, W2, b2, g2, be2, R2, R3);
    combine_kernel<128><<<BN, 128, 0, stream>>>(R2, R3, idx, R2); // h2 = R2

    // ---- Layer 3: h2 (D=128) -> h3 (C=256) in R3 ----
    sq_kernel<128><<<BN / 256, 256, 0, stream>>>(R2, sqb);
    knn_fused_kernel<128><<<KNN_GRID, 256, 0, stream>>>(R2, sqb, idx);
    mlp_gemm_kernel<128, 256><<<dim3(MB, 4), 256, 0, stream>>>(
        R2, W3, b3, g3, be3, R3, R1);
    combine_kernel<256><<<BN, 256, 0, stream>>>(R3, R1, idx, R3); // h3 = R3

    // ---- Head ----
    head_kernel<<<NBATCH, 256, 0, stream>>>(R3, Wf1, bf1, gf, bef, Wf2, bf2, out);
}

// Round 12
// 494.838 us; speedup vs baseline: 1.7521x; 1.0905x over previous
//
#include <hip/hip_runtime.h>
#include <cstdint>
#include <cstddef>

#define KNN 16
#define NPTS 256
#define NBATCH 128

static constexpr float BN_SCALE_F = 0.9999950000374997f; // 1/sqrt(1+1e-5)

__device__ inline unsigned int f32_ord(float f) {
    unsigned int u = __float_as_uint(f);
    return (u & 0x80000000u) ? ~u : (u | 0x80000000u);
}

// Ws column gap map: stride 160 (=0 mod 32); 16-blocks shifted by 4 banks.
__device__ __forceinline__ int wmap(int n) { return n + 4 * (n >> 4); }

// ---------------------------------------------------------------------------
// sq[t] = sum_d x[t][d]^2, sequential fmaf chain (matches reference assoc).
// ---------------------------------------------------------------------------
template<int D>
__global__ __launch_bounds__(256) void sq_kernel(const float* __restrict__ x,
                                                 float* __restrict__ sq) {
    const int t = blockIdx.x * 256 + threadIdx.x;
    const float* r = x + (size_t)t * D;
    float s = 0.f;
    #pragma unroll
    for (int d = 0; d < D; ++d) s = fmaf(r[d], r[d], s);
    sq[t] = s;
}

// ---------------------------------------------------------------------------
// FUSED kNN half-kernel: EXACT r8 body (proven 112 VGPR / no spills), but
// each block handles only 2 of the 4 j-tiles (half = bx&1) -> per-block work
// halves, grid doubles to 1024 (fixes r8's 2-blocks/CU starvation without
// the r9/r11 restructure that ballooned VGPR to 176).
// Output: sorted half-top-16 as (f32_ord(d2), j) uint2 pairs; a tiny merge
// kernel combines halves. d2 math ascending-d fmaf, (sqi+sqj)-2*acc,
// diag=+INF -> bit-identical to r1..r11.
// ---------------------------------------------------------------------------
template<int D>
__global__ __launch_bounds__(256) void knn_half_kernel(
        const float* __restrict__ x, const float* __restrict__ sq,
        uint2* __restrict__ halves) {
    constexpr int KS = (D >= 16) ? 16 : D;
    const int t  = threadIdx.x;
    const int tx = t & 15, ty = t >> 4;
    const int sr = t >> 2, sc = t & 3;
    const int bx = blockIdx.x;
    const int half = bx & 1;
    const int i0   = ((bx >> 1) & 3) * 64;
    const int b    = bx >> 3;
    const int base = b * NPTS;

    __shared__ float As[KS][68];
    __shared__ float Bs[KS][68];
    __shared__ float d2L[64][65];            // also reused as merge values
    __shared__ unsigned short Mi[64][68];    // merge indices

    unsigned int Lv[16], Li[16];
    #pragma unroll
    for (int q = 0; q < 16; ++q) { Lv[q] = 0xFFFFFFFFu; Li[q] = 0u; }

    for (int jt = half * 2; jt < half * 2 + 2; ++jt) {
        const int j0 = jt * 64;
        float acc[4][4] = {};
        for (int k0 = 0; k0 < D; k0 += KS) {
            if constexpr (D % 16 == 0) {
                const int r  = t >> 2;
                const int cq = (t & 3) * 4;
                const float4 va = *(const float4*)(x + (size_t)(base + i0 + r) * D + k0 + cq);
                const float4 vb = *(const float4*)(x + (size_t)(base + j0 + r) * D + k0 + cq);
                As[cq + 0][r] = va.x; As[cq + 1][r] = va.y;
                As[cq + 2][r] = va.z; As[cq + 3][r] = va.w;
                Bs[cq + 0][r] = vb.x; Bs[cq + 1][r] = vb.y;
                Bs[cq + 2][r] = vb.z; Bs[cq + 3][r] = vb.w;
            } else {
                for (int e = t; e < 64 * KS; e += 256) {
                    const int r = e / KS, c = e % KS;
                    As[c][r] = x[(size_t)(base + i0 + r) * D + k0 + c];
                    Bs[c][r] = x[(size_t)(base + j0 + r) * D + k0 + c];
                }
            }
            __syncthreads();
            #pragma unroll
            for (int kk = 0; kk < KS; ++kk) {
                const float4 av = *(const float4*)&As[kk][ty * 4];
                const float4 bv = *(const float4*)&Bs[kk][tx * 4];
                const float am[4] = {av.x, av.y, av.z, av.w};
                const float bm[4] = {bv.x, bv.y, bv.z, bv.w};
                #pragma unroll
                for (int m = 0; m < 4; ++m)
                    #pragma unroll
                    for (int n = 0; n < 4; ++n)
                        acc[m][n] = fmaf(am[m], bm[n], acc[m][n]);
            }
            __syncthreads();
        }

        // ---- epilogue: d2 tile into LDS (same arithmetic as r6/r8) ----
        float sqi[4], sqj[4];
        #pragma unroll
        for (int m = 0; m < 4; ++m) {
            sqi[m] = sq[base + i0 + ty * 4 + m];
            sqj[m] = sq[base + j0 + tx * 4 + m];
        }
        #pragma unroll
        for (int m = 0; m < 4; ++m) {
            const int gi = i0 + ty * 4 + m;
            #pragma unroll
            for (int n = 0; n < 4; ++n) {
                float v = (sqi[m] + sqj[n]) - 2.f * acc[m][n];
                if (gi == j0 + tx * 4 + n) v = INFINITY;
                d2L[ty * 4 + m][tx * 4 + n] = v;
            }
        }
        __syncthreads();

        // ---- insertion: thread (sr, sc) takes cands j = j0 + sc*16 + i ----
        #pragma unroll
        for (int i = 0; i < 16; ++i) {
            const unsigned int v = f32_ord(d2L[sr][sc * 16 + i]);
            const unsigned int j = (unsigned int)(j0 + sc * 16 + i);
            #pragma unroll
            for (int q = 15; q >= 1; --q) {
                const bool a = v < Lv[q];
                const bool c = v < Lv[q - 1];
                Lv[q] = a ? (c ? Lv[q - 1] : v) : Lv[q];
                Li[q] = a ? (c ? Li[q - 1] : j) : Li[q];
            }
            const bool a0 = v < Lv[0];
            Lv[0] = a0 ? v : Lv[0];
            Li[0] = a0 ? j : Li[0];
        }
        // next tile's d2L writes are fenced by the k-loop's barriers.
    }

    __syncthreads();   // all insertions done before d2L is reused for merge
    #pragma unroll
    for (int q = 0; q < 16; ++q) {
        d2L[sr][sc * 16 + q] = __uint_as_float(Lv[q]);
        Mi[sr][sc * 16 + q]  = (unsigned short)Li[q];
    }
    __syncthreads();

    if (t < 64) {
        const int row = t;
        int h[4];
        unsigned int cv[4], ci[4];
        #pragma unroll
        for (int c = 0; c < 4; ++c) {
            h[c]  = 0;
            cv[c] = __float_as_uint(d2L[row][c * 16]);
            ci[c] = Mi[row][c * 16];
        }
        uint2* op = halves + ((size_t)(base + i0 + row) * 2 + half) * 16;
        #pragma unroll
        for (int rd = 0; rd < 16; ++rd) {
            unsigned int bv = cv[0], bi = ci[0];
            int bc = 0;
            #pragma unroll
            for (int c = 1; c < 4; ++c) {
                const bool tk = (cv[c] < bv) | ((cv[c] == bv) & (ci[c] < bi));
                bv = tk ? cv[c] : bv;
                bi = tk ? ci[c] : bi;
                bc = tk ? c     : bc;
            }
            op[rd] = make_uint2(bv, bi);
            #pragma unroll
            for (int c = 0; c < 4; ++c) {
                if (c == bc) {
                    const int hn = h[c] + 1;
                    h[c] = hn;
                    if (hn < 16) {
                        cv[c] = __float_as_uint(d2L[row][c * 16 + hn]);
                        ci[c] = Mi[row][c * 16 + hn];
                    } else {
                        cv[c] = 0xFFFFFFFFu;
                    }
                }
            }
        }
    }
}

// ---------------------------------------------------------------------------
// Merge the two sorted half-lists per row (16+16 -> top-16). Half-0 covers
// j<128, half-1 j>=128; lexicographic (value, index) compare reproduces
// lax.top_k exactly. One thread per row.
// ---------------------------------------------------------------------------
__global__ __launch_bounds__(256) void knn_merge_kernel(
        const uint2* __restrict__ halves, int* __restrict__ idx) {
    const int ig = blockIdx.x * 256 + threadIdx.x;
    const uint2* A = halves + (size_t)ig * 32;
    const uint2* B = A + 16;
    int ha = 0, hb = 0;
    uint2 a = A[0], c = B[0];
    int* op = idx + (size_t)ig * KNN;
    #pragma unroll
    for (int s = 0; s < 16; ++s) {
        const bool tb = (c.x < a.x) | ((c.x == a.x) & (c.y < a.y));
        op[s] = (int)(tb ? c.y : a.y);
        if (tb) {
            ++hb;
            c = (hb < 16) ? B[hb] : make_uint2(0xFFFFFFFFu, 0xFFFFFFFFu);
        } else {
            ++ha;
            a = (ha < 16) ? A[ha] : make_uint2(0xFFFFFFFFu, 0xFFFFFFFFu);
        }
    }
}

// ---------------------------------------------------------------------------
// Factorized edge-MLP GEMM (unchanged from r6/r7/r8).
// ---------------------------------------------------------------------------
template<int D, int C>
__global__ __launch_bounds__(256) void mlp_gemm_kernel(
        const float* __restrict__ x, const float* __restrict__ W,
        const float* __restrict__ bias, const float* __restrict__ g,
        const float* __restrict__ be,
        float* __restrict__ A, float* __restrict__ Bv) {
    constexpr int BM = 128;
    constexpr int KT = (D >= 16) ? 16 : D;
    const int t  = threadIdx.x;
    const int m0 = blockIdx.x * BM;
    const int n0 = blockIdx.y * 128;
    const int tx = t & 15;   // col group (8 cols)
    const int ty = t >> 4;   // row group (8 rows)

    __shared__ float Xs[KT][BM + 4];
    __shared__ float Ws[KT][160];      // gapped columns via wmap()

    float acc[8][8] = {};

    for (int k0 = 0; k0 < D; k0 += KT) {
        if constexpr (D % 16 == 0) {
            const int r  = t >> 1;          // 0..127
            const int cq = (t & 1) * 8;     // 0 or 8
            const float* src = x + (size_t)(m0 + r) * D + k0 + cq;
            const float4 v0 = *(const float4*)(src);
            const float4 v1 = *(const float4*)(src + 4);
            Xs[cq + 0][r] = v0.x; Xs[cq + 1][r] = v0.y;
            Xs[cq + 2][r] = v0.z; Xs[cq + 3][r] = v0.w;
            Xs[cq + 4][r] = v1.x; Xs[cq + 5][r] = v1.y;
            Xs[cq + 6][r] = v1.z; Xs[cq + 7][r] = v1.w;
        } else {
            for (int e = t; e < BM * KT; e += 256) {
                const int r = e / KT, c = e % KT;
                Xs[c][r] = x[(size_t)(m0 + r) * D + k0 + c];
            }
        }
        if constexpr (D % 16 == 0) {
            const int wk = t >> 4;           // 0..15 (k row)
            const int nq = (t & 15) * 8;     // col offset (8-block)
            const int mb = wmap(nq);         // mapped col base (contiguous 8)
            const int gn = n0 + nq;
            const int kr = k0 + wk;
            if (gn < C) {
                const float* pt = W + (size_t)kr * C + gn;
                const float* pb = W + (size_t)(D + kr) * C + gn;
                const float4 t0 = *(const float4*)(pt);
                const float4 t1 = *(const float4*)(pt + 4);
                const float4 b0 = *(const float4*)(pb);
                const float4 b1 = *(const float4*)(pb + 4);
                *(float4*)&Ws[wk][mb]     = make_float4(t0.x - b0.x, t0.y - b0.y,
                                                        t0.z - b0.z, t0.w - b0.w);
                *(float4*)&Ws[wk][mb + 4] = make_float4(t1.x - b1.x, t1.y - b1.y,
                                                        t1.z - b1.z, t1.w - b1.w);
            } else {
                const float* pb = W + (size_t)(D + kr) * C + (gn - C);
                *(float4*)&Ws[wk][mb]     = *(const float4*)(pb);
                *(float4*)&Ws[wk][mb + 4] = *(const float4*)(pb + 4);
            }
        } else {
            for (int e = t; e < KT * 128; e += 256) {
                const int k = e >> 7, n = e & 127;
                const int gn = n0 + n, kr = k0 + k;
                Ws[k][wmap(n)] = (gn < C)
                    ? W[(size_t)kr * C + gn] - W[(size_t)(D + kr) * C + gn]
                    : W[(size_t)(D + kr) * C + (gn - C)];
            }
        }
        __syncthreads();

        const int mc = wmap(tx * 8);
        #pragma unroll
        for (int kk = 0; kk < KT; ++kk) {
            float xm[8], wn[8];
            *(float4*)&xm[0] = *(const float4*)&Xs[kk][ty * 8];
            *(float4*)&xm[4] = *(const float4*)&Xs[kk][ty * 8 + 4];
            *(float4*)&wn[0] = *(const float4*)&Ws[kk][mc];
            *(float4*)&wn[4] = *(const float4*)&Ws[kk][mc + 4];
            #pragma unroll
            for (int m = 0; m < 8; ++m)
                #pragma unroll
                for (int n = 0; n < 8; ++n)
                    acc[m][n] = fmaf(xm[m], wn[n], acc[m][n]);
        }
        __syncthreads();
    }

    const int gn = n0 + tx * 8;
    if (gn < C) {
        float fac[8];
        #pragma unroll
        for (int e = 0; e < 8; ++e) fac[e] = g[gn + e] * BN_SCALE_F;
        #pragma unroll
        for (int m = 0; m < 8; ++m) {
            float o[8];
            #pragma unroll
            for (int e = 0; e < 8; ++e) o[e] = fac[e] * acc[m][e];
            float* dst = A + (size_t)(m0 + ty * 8 + m) * C + gn;
            *(float4*)(dst)     = make_float4(o[0], o[1], o[2], o[3]);
            *(float4*)(dst + 4) = make_float4(o[4], o[5], o[6], o[7]);
        }
    } else {
        const int cb = gn - C;
        float fac[8], bb[8], bee[8];
        #pragma unroll
        for (int e = 0; e < 8; ++e) {
            fac[e] = g[cb + e] * BN_SCALE_F;
            bb[e]  = bias[cb + e];
            bee[e] = be[cb + e];
        }
        #pragma unroll
        for (int m = 0; m < 8; ++m) {
            float o[8];
            #pragma unroll
            for (int e = 0; e < 8; ++e)
                o[e] = fmaf(fac[e], acc[m][e] + bb[e], bee[e]);
            float* dst = Bv + (size_t)(m0 + ty * 8 + m) * C + cb;
            *(float4*)(dst)     = make_float4(o[0], o[1], o[2], o[3]);
            *(float4*)(dst + 4) = make_float4(o[4], o[5], o[6], o[7]);
        }
    }
}

// ---------------------------------------------------------------------------
// Combine: out[i][c] = relu(A[i][c] + max_{j in knn(i)} Bv[j][c]). out aliases A.
// ---------------------------------------------------------------------------
template<int C>
__global__ __launch_bounds__(C) void combine_kernel(
        const float* A, const float* __restrict__ Bv,
        const int* __restrict__ idx, float* out) {
    const int bi = blockIdx.x;
    const int c  = threadIdx.x;
    __shared__ int nbr[KNN];
    if (c < KNN) nbr[c] = idx[(size_t)bi * KNN + c];
    __syncthreads();
    const int b0 = bi & ~255;
    float mx = -INFINITY;
    #pragma unroll
    for (int kk = 0; kk < KNN; ++kk)
        mx = fmaxf(mx, Bv[(size_t)(b0 + nbr[kk]) * C + c]);
    float a = A[(size_t)bi * C + c];
    out[(size_t)bi * C + c] = fmaxf(a + mx, 0.f);
}

// ---------------------------------------------------------------------------
// Head: global max-pool over N, then 2 tiny FCs. One block per batch.
// ---------------------------------------------------------------------------
__global__ __launch_bounds__(256) void head_kernel(
        const float* __restrict__ h3, const float* __restrict__ Wf1,
        const float* __restrict__ bf1, const float* __restrict__ gf,
        const float* __restrict__ bef, const float* __restrict__ Wf2,
        const float* __restrict__ bf2, float* __restrict__ out) {
    const int b   = blockIdx.x;
    const int tid = threadIdx.x;
    __shared__ float p[256];
    __shared__ float f[128];
    const float* hb = h3 + (size_t)b * NPTS * 256;
    float mx = -INFINITY;
    for (int n = 0; n < NPTS; ++n) mx = fmaxf(mx, hb[(size_t)n * 256 + tid]);
    p[tid] = mx;
    __syncthreads();
    if (tid < 128) {
        float acc = bf1[tid];
        for (int d = 0; d < 256; ++d)
            acc = fmaf(p[d], Wf1[(size_t)d * 128 + tid], acc);
        float v = gf[tid] * (acc * BN_SCALE_F) + bef[tid];
        f[tid] = fmaxf(v, 0.f);
    }
    __syncthreads();
    if (tid < 12) {
        float acc = bf2[tid];
        for (int d = 0; d < 128; ++d)
            acc = fmaf(f[d], Wf2[(size_t)d * 12 + tid], acc);
        out[(size_t)b * 12 + tid] = acc;
    }
}

extern "C" void kernel_launch(void* const* d_in, const int* in_sizes, int n_in,
                              void* d_out, int out_size, void* d_ws, size_t ws_size,
                              hipStream_t stream) {
    const float* x   = (const float*)d_in[0];
    const float* W1  = (const float*)d_in[1];
    const float* b1  = (const float*)d_in[2];
    const float* g1  = (const float*)d_in[3];
    const float* be1 = (const float*)d_in[4];
    const float* W2  = (const float*)d_in[5];
    const float* b2  = (const float*)d_in[6];
    const float* g2  = (const float*)d_in[7];
    const float* be2 = (const float*)d_in[8];
    const float* W3  = (const float*)d_in[9];
    const float* b3  = (const float*)d_in[10];
    const float* g3  = (const float*)d_in[11];
    const float* be3 = (const float*)d_in[12];
    const float* Wf1 = (const float*)d_in[13];
    const float* bf1 = (const float*)d_in[14];
    const float* gf  = (const float*)d_in[15];
    const float* bef = (const float*)d_in[16];
    const float* Wf2 = (const float*)d_in[17];
    const float* bf2 = (const float*)d_in[18];
    float* out = (float*)d_out;

    char* ws = (char*)d_ws;
    const size_t idx_bytes = (size_t)NBATCH * NPTS * KNN * sizeof(int);   // 2 MB
    const size_t reg_bytes = (size_t)NBATCH * NPTS * 256 * sizeof(float); // 32 MB
    int*   idx = (int*)ws;
    float* R1  = (float*)(ws + idx_bytes);
    float* R2  = (float*)(ws + idx_bytes + reg_bytes);
    float* R3  = (float*)(ws + idx_bytes + 2 * reg_bytes);
    float* sqb = (float*)(ws + idx_bytes + 3 * reg_bytes);                // 128 KB
    uint2* hv  = (uint2*)R3;   // 8 MB half-lists scratch; R3 dead during knn

    const int BN = NBATCH * NPTS;        // 32768 points
    const int KNN_GRID = NBATCH * 8;     // 1024 blocks (64 rows x j-half each)
    const int MRG_GRID = BN / 256;       // 128 blocks
    const int MB = BN / 128;             // 256 m-blocks for the MLP GEMM

    // ---- Layer 1: x (D=6) -> h1 (C=64) in R1 ----
    sq_kernel<6><<<BN / 256, 256, 0, stream>>>(x, sqb);
    knn_half_kernel<6><<<KNN_GRID, 256, 0, stream>>>(x, sqb, hv);
    knn_merge_kernel<<<MRG_GRID, 256, 0, stream>>>(hv, idx);
    mlp_gemm_kernel<6, 64><<<dim3(MB, 1), 256, 0, stream>>>(
        x, W1, b1, g1, be1, R1, R2);
    combine_kernel<64><<<BN, 64, 0, stream>>>(R1, R2, idx, R1);   // h1 = R1

    // ---- Layer 2: h1 (D=64) -> h2 (C=128) in R2 ----
    sq_kernel<64><<<BN / 256, 256, 0, stream>>>(R1, sqb);
    knn_half_kernel<64><<<KNN_GRID, 256, 0, stream>>>(R1, sqb, hv);
    knn_merge_kernel<<<MRG_GRID, 256, 0, stream>>>(hv, idx);
    mlp_gemm_kernel<64, 128><<<dim3(MB, 2), 256, 0, stream>>>(
        R1, W2, b2, g2, be2, R2, R3);
    combine_kernel<128><<<BN, 128, 0, stream>>>(R2, R3, idx, R2); // h2 = R2

    // ---- Layer 3: h2 (D=128) -> h3 (C=256) in R3 ----
    // hv lives at R3 start; mlp writes R3 only AFTER merge has consumed hv.
    sq_kernel<128><<<BN / 256, 256, 0, stream>>>(R2, sqb);
    knn_half_kernel<128><<<KNN_GRID, 256, 0, stream>>>(R2, sqb, hv);
    knn_merge_kernel<<<MRG_GRID, 256, 0, stream>>>(hv, idx);
    mlp_gemm_kernel<128, 256><<<dim3(MB, 4), 256, 0, stream>>>(
        R2, W3, b3, g3, be3, R3, R1);
    combine_kernel<256><<<BN, 256, 0, stream>>>(R3, R1, idx, R3); // h3 = R3

    // ---- Head ----
    head_kernel<<<NBATCH, 256, 0, stream>>>(R3, Wf1, bf1, gf, bef, Wf2, bf2, out);
}